// Round 6
// baseline (109.847 us; speedup 1.0000x reference)
//
#include <hip/hip_runtime.h>

typedef __attribute__((ext_vector_type(8))) short short8;
typedef __attribute__((ext_vector_type(4))) float f32x4;

#define THREADS 512

__device__ __forceinline__ float b2f(unsigned short u) {
  return __uint_as_float(((unsigned int)u) << 16);
}
__device__ __forceinline__ unsigned short f2b(float f) {
  unsigned int i = __float_as_uint(f);
  unsigned int r = (i + 0x7fffu + ((i >> 16) & 1u)) >> 16;
  return (unsigned short)r;
}
__device__ __forceinline__ void unpack2(unsigned int u, float& a, float& b) {
  a = __uint_as_float(u << 16);
  b = __uint_as_float(u & 0xffff0000u);
}
// row-dependent 2-bit swizzle for 64B-row A-fragment tiles
__device__ __forceinline__ unsigned int s2f(unsigned int r) {
  return (r + (r >> 2)) & 3u;
}

// ---------------- pack kernel ----------------
// Bpack  (stage-1 B): [((g*8+ks)*64+lane)*8+j] = Wcat[d=ks*32+(lane>>4)*8+j][col=g*16+(lane&15)]
//   Wcat cols: [0,512)=We0 (col=e*64+h), [512,768)=Wg0a, [768,896)=Wg1a
// Bpack2 (e1 B): [(((e*2+ct)*2+ks)*64+lane)*8+j] = We1[e][h=ks*32+(lane>>4)*8+j][k=ct*16+(lane&15)]
// Bpack3 (gate B): [(u*64+lane)*8+j] = col<8 ? Wg[u][k=(lane>>4)*8+j][col] : 0   (col=lane&15)
__global__ void pack_kernel(const float* __restrict__ We0,
                            const float* __restrict__ Wg0a,
                            const float* __restrict__ Wg1a,
                            const float* __restrict__ be0,
                            const float* __restrict__ bg0a,
                            const float* __restrict__ bg1a,
                            const float* __restrict__ We1,
                            const float* __restrict__ Wg0b,
                            const float* __restrict__ Wg1b,
                            unsigned short* __restrict__ Bpack,
                            float* __restrict__ bcat,
                            unsigned short* __restrict__ Bpack2,
                            unsigned short* __restrict__ Bpack3) {
  int gid = blockIdx.x * blockDim.x + threadIdx.x;
  if (gid < 229376) {
    int j = gid & 7;
    int lane = (gid >> 3) & 63;
    int ks = (gid >> 9) & 7;
    int g = gid >> 12;
    int d = ks * 32 + (lane >> 4) * 8 + j;
    int col = g * 16 + (lane & 15);
    float v;
    if (col < 512) {
      v = We0[((col >> 6) * 256 + d) * 64 + (col & 63)];
    } else if (col < 768) {
      int c = col - 512;
      v = Wg0a[((c >> 5) * 256 + d) * 32 + (c & 31)];
    } else {
      int c = col - 768;
      v = Wg1a[((c >> 5) * 256 + d) * 32 + (c & 31)];
    }
    Bpack[gid] = f2b(v);
    if (gid < 896) {
      float bv;
      if (gid < 512) bv = be0[gid];
      else if (gid < 768) bv = bg0a[gid - 512];
      else bv = bg1a[gid - 768];
      bcat[gid] = bv;
    }
  } else if (gid < 245760) {
    int i = gid - 229376;           // 0..16383
    int j = i & 7;
    int lane = (i >> 3) & 63;
    int ks = (i >> 9) & 1;
    int ct = (i >> 10) & 1;
    int e = i >> 11;
    int h = ks * 32 + (lane >> 4) * 8 + j;
    int k = ct * 16 + (lane & 15);
    Bpack2[i] = f2b(We1[(e * 64 + h) * 32 + k]);
  } else if (gid < 251904) {
    int i = gid - 245760;           // 0..6143
    int j = i & 7;
    int lane = (i >> 3) & 63;
    int u = i >> 9;                 // 0..11
    int k = (lane >> 4) * 8 + j;    // hidden index 0..31
    int col = lane & 15;
    float v = 0.f;
    if (col < 8) {
      v = (u < 8) ? Wg0b[(u * 32 + k) * 8 + col]
                  : Wg1b[((u - 8) * 32 + k) * 8 + col];
    }
    Bpack3[i] = f2b(v);
  }
}

// ---------------- fused kernel ----------------
// 2048 blocks x 512 threads, 32 rows/block.  LDS = 80128 B -> 2 blocks/CU.
//
// MFMA conventions (16x16x32 bf16, verified by stage-1 GEMM):
//   A-frag: lane l supplies A[row=l&15][k=(l>>4)*8+j]
//   B-frag: lane l supplies B[k=(l>>4)*8+j][col=l&15]
//   C/D  : lane l holds  D[row=(l>>4)*4+reg][col=l&15]
__global__ __launch_bounds__(THREADS, 4) void fused_kernel(
    const float* __restrict__ x,
    const unsigned short* __restrict__ Bpack,
    const float* __restrict__ bcat,
    const unsigned short* __restrict__ Bpack2,
    const unsigned short* __restrict__ Bpack3,
    const float* __restrict__ be1,
    const float* __restrict__ bg0b,
    const float* __restrict__ bg1b,
    float* __restrict__ out)
{
  __shared__ __align__(16) struct {
    union {
      struct {
        unsigned short xt[32 * 256];     // x tile bf16 swizzled (P1..P2)      16384 B
        unsigned short YgA[12 * 32 * 32];// gate hidden A-frags (epi..P3)      24576 B
      } a;
      unsigned short x1A[8 * 32 * 64];   // x1 A-frags for e1 (P4..P5)         32768 B
    } U;                                  // 40960 B
    union {
      unsigned short e0B[16 * 1032];     // e0 B-frags, pair-stride 1032 els   33024 B
      unsigned short e1buf[32 * 274];    // e1 bf16 (P5..P6)                   17536 B
    } A2;
    unsigned short g0L[32 * 64];         // g0 probs bf16 [b][g*8+e]            4096 B
    unsigned short g1L[32 * 32];         // g1 probs bf16 [b][t*8+e]            2048 B
  } S;                                    // total 80128 B

  const int tid = threadIdx.x;
  const int bid = blockIdx.x;
  const int lane = tid & 63;
  const int wave = tid >> 6;
  const int lr = lane & 15;
  const int lq = lane >> 4;

  // persistent e1 B-fragments (16 VGPRs)
  short8 b2r[4];
#pragma unroll
  for (int ct = 0; ct < 2; ++ct)
#pragma unroll
    for (int k2 = 0; k2 < 2; ++k2)
      b2r[ct * 2 + k2] = *(const short8*)(Bpack2 + (size_t)(wave * 4 + ct * 2 + k2) * 512 + lane * 8);

  // ---- P1: x tile (32x256 fp32) -> LDS bf16, XOR-swizzled ----
  {
    const float4* xg = (const float4*)(x + (size_t)bid * 32 * 256);
    char* xb = (char*)S.U.a.xt;
#pragma unroll
    for (int i = 0; i < 4; ++i) {
      int idx = tid + i * THREADS;          // float4 index 0..2047
      float4 f = xg[idx];
      int row = idx >> 6;
      unsigned int boff = (unsigned int)(idx & 63) * 8;
      unsigned int u0 = ((unsigned int)f2b(f.y) << 16) | f2b(f.x);
      unsigned int u1 = ((unsigned int)f2b(f.w) << 16) | f2b(f.z);
      unsigned int addr = ((unsigned int)row * 512 + boff) ^ (((unsigned int)(row & 7)) << 4);
      *(uint2*)(xb + addr) = make_uint2(u0, u1);
    }
  }
  __syncthreads();

  // ---- P2: stage-1 GEMM  [32x896] = relu(x @ Wcat + bcat) ----
  {
    float bias_r[7];
#pragma unroll
    for (int ng = 0; ng < 7; ++ng) bias_r[ng] = bcat[(wave * 7 + ng) * 16 + lr];

    f32x4 acc[2][7];
#pragma unroll
    for (int mt = 0; mt < 2; ++mt)
#pragma unroll
      for (int ng = 0; ng < 7; ++ng) acc[mt][ng] = {0.f, 0.f, 0.f, 0.f};

    const char* xb = (const char*)S.U.a.xt;
    const unsigned int sw = ((unsigned int)(lr & 7)) << 4;
    const unsigned int a0base = (unsigned int)lr * 512;
    const unsigned int a1base = (unsigned int)(16 + lr) * 512;
    const unsigned short* bp = Bpack + (size_t)(wave * 7) * 4096 + (size_t)lane * 8;

#pragma unroll
    for (int ks = 0; ks < 8; ++ks) {
      unsigned int ko = (unsigned int)ks * 64 + (unsigned int)lq * 16;
      short8 a0 = *(const short8*)(xb + ((a0base + ko) ^ sw));
      short8 a1 = *(const short8*)(xb + ((a1base + ko) ^ sw));
#pragma unroll
      for (int ng = 0; ng < 7; ++ng) {
        short8 b = *(const short8*)(bp + (size_t)(ng * 8 + ks) * 512);
        acc[0][ng] = __builtin_amdgcn_mfma_f32_16x16x32_bf16(a0, b, acc[0][ng], 0, 0, 0);
        acc[1][ng] = __builtin_amdgcn_mfma_f32_16x16x32_bf16(a1, b, acc[1][ng], 0, 0, 0);
      }
    }

    // epilogue: bias+relu.
    //  e0 cols -> e0B in combine-B-frag order: element e0[b][e][h]
    //    (p=b>>1, bi=b&1, n=h>>4, hcol=h&15) at el = p*1032 + n*256 + (bi*16+hcol)*8 + e
    //  gate cols -> YgA[u][row][k] A-frags, swizzled chunk kq^s2f(row)
#pragma unroll
    for (int ng = 0; ng < 7; ++ng) {
      int gcol = wave * 7 + ng;
      float bias = bias_r[ng];
      if (gcol < 32) {
        int e = gcol >> 2;
        int n = gcol & 3;
        int base_el = n * 256 + lr * 8 + e;
#pragma unroll
        for (int mt = 0; mt < 2; ++mt) {
#pragma unroll
          for (int rg = 0; rg < 4; ++rg) {
            int b = mt * 16 + lq * 4 + rg;
            float v = acc[mt][ng][rg] + bias;
            S.A2.e0B[(b >> 1) * 1032 + (b & 1) * 128 + base_el] = f2b(v > 0.f ? v : 0.f);
          }
        }
      } else {
        int c2 = gcol - 32;              // 0..23
        int u = c2 >> 1;
        int h = (c2 & 1) * 16 + lr;      // 0..31
        int kqw = h >> 3;
        int jw = h & 7;
#pragma unroll
        for (int mt = 0; mt < 2; ++mt) {
#pragma unroll
          for (int rg = 0; rg < 4; ++rg) {
            int row = mt * 16 + lq * 4 + rg;
            float v = acc[mt][ng][rg] + bias;
            S.U.a.YgA[u * 1024 + row * 32 + ((kqw ^ (int)s2f(row)) << 3) + jw] =
                f2b(v > 0.f ? v : 0.f);
          }
        }
      }
    }
  }
  __syncthreads();

  // ---- P3: gate logits via MFMA + cross-lane softmax ----
  // item id = u*2 + mt; wave handles ids 3w..3w+2 (24 items total)
  {
#pragma unroll
    for (int i = 0; i < 3; ++i) {
      int id = wave * 3 + i;
      int u = id >> 1;
      int mtq = id & 1;
      int row = lr + mtq * 16;           // batch row of this A row
      const char* yb = (const char*)S.U.a.YgA;
      short8 af = *(const short8*)(yb + u * 2048 + row * 64 +
                                   ((((unsigned int)lq) ^ s2f(row)) << 4));
      short8 bf = *(const short8*)(Bpack3 + (size_t)(u * 64 + lane) * 8);
      f32x4 dl = {0.f, 0.f, 0.f, 0.f};
      dl = __builtin_amdgcn_mfma_f32_16x16x32_bf16(af, bf, dl, 0, 0, 0);

      int col = lr;
      float bias = 0.f;
      if (col < 8) bias = (u < 8) ? bg0b[u * 8 + col] : bg1b[(u - 8) * 8 + col];
#pragma unroll
      for (int reg = 0; reg < 4; ++reg) {
        float lg = dl[reg] + bias;
        float m = lg;
        m = fmaxf(m, __shfl_xor(m, 1));
        m = fmaxf(m, __shfl_xor(m, 2));
        m = fmaxf(m, __shfl_xor(m, 4));
        float ex = __expf(lg - m);
        float s = ex;
        s += __shfl_xor(s, 1);
        s += __shfl_xor(s, 2);
        s += __shfl_xor(s, 4);
        float pv = ex / s;
        if (col < 8) {
          int b = mtq * 16 + lq * 4 + reg;
          if (u < 8) S.g0L[b * 64 + u * 8 + col] = f2b(pv);
          else       S.g1L[b * 32 + (u - 8) * 8 + col] = f2b(pv);
        }
      }
    }
  }
  __syncthreads();

  // ---- P4: x1 = g0 @ e0 via block-diagonal MFMA ----
  // pair p (rows 2p,2p+1): A(16x32): A[(bi*8+g)][bi'*8+e] = (bi==bi') g0[2p+bi][g][e]
  // B = e0B[p][n];  D[row=(bi*8+g)][col=hcol] = x1[2p+bi][g][n*16+hcol]
  {
    f32x4 xacc[2][4];
#pragma unroll
    for (int pi = 0; pi < 2; ++pi)
#pragma unroll
      for (int n = 0; n < 4; ++n) xacc[pi][n] = {0.f, 0.f, 0.f, 0.f};

    const short8 zero8 = {0, 0, 0, 0, 0, 0, 0, 0};
    const char* e0b = (const char*)S.A2.e0B;
#pragma unroll
    for (int pi = 0; pi < 2; ++pi) {
      int p = wave * 2 + pi;
      int kqh = lq & 1;
      int rtop = lr >> 3;
      int g = lane & 7;
      short8 ga = *(const short8*)&S.g0L[(2 * p + kqh) * 64 + g * 8];
      bool sel = (lane < 32) && (rtop == kqh);
      ga = sel ? ga : zero8;
#pragma unroll
      for (int n = 0; n < 4; ++n) {
        short8 bb = *(const short8*)(e0b + p * 2064 + n * 512 + (lane & 31) * 16);
        xacc[pi][n] = __builtin_amdgcn_mfma_f32_16x16x32_bf16(ga, bb, xacc[pi][n], 0, 0, 0);
      }
    }
    // write x1 -> x1A (bf16 A-frags for e1): element (E=g, b, h) at
    // byte = E*4096 + b*128 + (((h>>3)^(b&7))<<4) + (h&7)*2
    char* x1b = (char*)S.U.x1A;
#pragma unroll
    for (int pi = 0; pi < 2; ++pi) {
      int p = wave * 2 + pi;
#pragma unroll
      for (int n = 0; n < 4; ++n) {
#pragma unroll
        for (int reg = 0; reg < 4; ++reg) {
          int row16 = lq * 4 + reg;
          int bi = row16 >> 3, g = row16 & 7;
          int b = 2 * p + bi;
          int h = n * 16 + lr;
          *(unsigned short*)(x1b + g * 4096 + b * 128 +
                             ((((unsigned int)(h >> 3)) ^ ((unsigned int)b & 7)) << 4) +
                             (h & 7) * 2) = f2b(xacc[pi][n][reg]);
        }
      }
    }
  }
  __syncthreads();

  // ---- P5: e1 = relu(x1 @ We1 + be1) via MFMA.  wave w = expert w ----
  {
    const int w = wave;
    f32x4 eacc[2][2];
#pragma unroll
    for (int mt = 0; mt < 2; ++mt)
#pragma unroll
      for (int ct = 0; ct < 2; ++ct) eacc[mt][ct] = {0.f, 0.f, 0.f, 0.f};

    const char* x1b = (const char*)S.U.x1A;
#pragma unroll
    for (int ks = 0; ks < 2; ++ks) {
#pragma unroll
      for (int mt = 0; mt < 2; ++mt) {
        int bp_ = lr + 16 * mt;
        short8 a = *(const short8*)(x1b + w * 4096 + bp_ * 128 +
                    ((((unsigned int)(ks * 4 + lq)) ^ ((unsigned int)bp_ & 7)) << 4));
        eacc[mt][0] = __builtin_amdgcn_mfma_f32_16x16x32_bf16(a, b2r[0 * 2 + ks], eacc[mt][0], 0, 0, 0);
        eacc[mt][1] = __builtin_amdgcn_mfma_f32_16x16x32_bf16(a, b2r[1 * 2 + ks], eacc[mt][1], 0, 0, 0);
      }
    }
    unsigned short* e1buf = S.A2.e1buf;
#pragma unroll
    for (int ct = 0; ct < 2; ++ct) {
      int k = ct * 16 + lr;
      float bias = be1[w * 32 + k];
#pragma unroll
      for (int mt = 0; mt < 2; ++mt) {
#pragma unroll
        for (int rg = 0; rg < 4; ++rg) {
          int row = mt * 16 + lq * 4 + rg;
          float v = eacc[mt][ct][rg] + bias;
          e1buf[row * 274 + w * 34 + k] = f2b(v > 0.f ? v : 0.f);
        }
      }
    }
  }
  __syncthreads();

  // ---- P6: out[t][k] = sum_e g1[t][e]*e1[e][k].  thread (r,j) owns k={2j,2j+1} ----
  {
    const int r = tid >> 4;
    const int j = tid & 15;
    const unsigned short* e1buf = S.A2.e1buf;
    short8 gvt[4];                     // one short8 per task t (8 expert probs)
#pragma unroll
    for (int t = 0; t < 4; ++t)
      gvt[t] = *(const short8*)&S.g1L[r * 32 + t * 8];
    float o0[4], o1[4];
#pragma unroll
    for (int t = 0; t < 4; ++t) { o0[t] = 0.f; o1[t] = 0.f; }
#pragma unroll
    for (int q = 0; q < 8; ++q) {
      unsigned int uu = *(const unsigned int*)&e1buf[r * 274 + q * 34 + j * 2];
      float ev0, ev1;
      unpack2(uu, ev0, ev1);
#pragma unroll
      for (int t = 0; t < 4; ++t) {
        float gt = b2f((unsigned short)gvt[t][q]);
        o0[t] += gt * ev0;
        o1[t] += gt * ev1;
      }
    }
    float* op = out + ((size_t)bid * 32 + r) * 128 + j * 2;
#pragma unroll
    for (int t = 0; t < 4; ++t) {
      *(float2*)(op + t * 32) = make_float2(o0[t], o1[t]);
    }
  }
}

extern "C" void kernel_launch(void* const* d_in, const int* in_sizes, int n_in,
                              void* d_out, int out_size, void* d_ws, size_t ws_size,
                              hipStream_t stream) {
  const float* x    = (const float*)d_in[0];
  const float* We0  = (const float*)d_in[1];
  const float* be0  = (const float*)d_in[2];
  const float* We1  = (const float*)d_in[3];
  const float* be1  = (const float*)d_in[4];
  const float* Wg0a = (const float*)d_in[5];
  const float* bg0a = (const float*)d_in[6];
  const float* Wg0b = (const float*)d_in[7];
  const float* bg0b = (const float*)d_in[8];
  const float* Wg1a = (const float*)d_in[9];
  const float* bg1a = (const float*)d_in[10];
  const float* Wg1b = (const float*)d_in[11];
  const float* bg1b = (const float*)d_in[12];

  unsigned short* Bpack  = (unsigned short*)d_ws;
  float*          bcat   = (float*)((char*)d_ws + 458752);
  unsigned short* Bpack2 = (unsigned short*)((char*)d_ws + 462336);
  unsigned short* Bpack3 = (unsigned short*)((char*)d_ws + 495104);

  pack_kernel<<<492, 512, 0, stream>>>(We0, Wg0a, Wg1a, be0, bg0a, bg1a, We1,
                                       Wg0b, Wg1b, Bpack, bcat, Bpack2, Bpack3);
  fused_kernel<<<2048, 512, 0, stream>>>(x, Bpack, bcat, Bpack2, Bpack3, be1,
                                         bg0b, bg1b, (float*)d_out);
}

// Round 7
// 107.713 us; speedup vs baseline: 1.0198x; 1.0198x over previous
//
#include <hip/hip_runtime.h>

typedef __attribute__((ext_vector_type(8))) short short8;
typedef __attribute__((ext_vector_type(4))) float f32x4;

#define THREADS 512

__device__ __forceinline__ float b2f(unsigned short u) {
  return __uint_as_float(((unsigned int)u) << 16);
}
__device__ __forceinline__ unsigned short f2b(float f) {
  unsigned int i = __float_as_uint(f);
  unsigned int r = (i + 0x7fffu + ((i >> 16) & 1u)) >> 16;
  return (unsigned short)r;
}
__device__ __forceinline__ void unpack2(unsigned int u, float& a, float& b) {
  a = __uint_as_float(u << 16);
  b = __uint_as_float(u & 0xffff0000u);
}
// row-dependent 2-bit swizzle for 64B-row A-fragment tiles
__device__ __forceinline__ unsigned int s2f(unsigned int r) {
  return (r + (r >> 2)) & 3u;
}

// ---------------- pack kernel ----------------
// Bpack  (stage-1 B): [((g*8+ks)*64+lane)*8+j] = Wcat[d=ks*32+(lane>>4)*8+j][col=g*16+(lane&15)]
//   Wcat cols: [0,512)=We0 (col=e*64+h), [512,768)=Wg0a, [768,896)=Wg1a
// Bpack2 (e1 B): [(((e*2+ct)*2+ks)*64+lane)*8+j] = We1[e][h=ks*32+(lane>>4)*8+j][k=ct*16+(lane&15)]
// Bpack3 (gate B): [(u*64+lane)*8+j] = col<8 ? Wg[u][k=(lane>>4)*8+j][col] : 0   (col=lane&15)
__global__ void pack_kernel(const float* __restrict__ We0,
                            const float* __restrict__ Wg0a,
                            const float* __restrict__ Wg1a,
                            const float* __restrict__ be0,
                            const float* __restrict__ bg0a,
                            const float* __restrict__ bg1a,
                            const float* __restrict__ We1,
                            const float* __restrict__ Wg0b,
                            const float* __restrict__ Wg1b,
                            unsigned short* __restrict__ Bpack,
                            float* __restrict__ bcat,
                            unsigned short* __restrict__ Bpack2,
                            unsigned short* __restrict__ Bpack3) {
  int gid = blockIdx.x * blockDim.x + threadIdx.x;
  if (gid < 229376) {
    int j = gid & 7;
    int lane = (gid >> 3) & 63;
    int ks = (gid >> 9) & 7;
    int g = gid >> 12;
    int d = ks * 32 + (lane >> 4) * 8 + j;
    int col = g * 16 + (lane & 15);
    float v;
    if (col < 512) {
      v = We0[((col >> 6) * 256 + d) * 64 + (col & 63)];
    } else if (col < 768) {
      int c = col - 512;
      v = Wg0a[((c >> 5) * 256 + d) * 32 + (c & 31)];
    } else {
      int c = col - 768;
      v = Wg1a[((c >> 5) * 256 + d) * 32 + (c & 31)];
    }
    Bpack[gid] = f2b(v);
    if (gid < 896) {
      float bv;
      if (gid < 512) bv = be0[gid];
      else if (gid < 768) bv = bg0a[gid - 512];
      else bv = bg1a[gid - 768];
      bcat[gid] = bv;
    }
  } else if (gid < 245760) {
    int i = gid - 229376;           // 0..16383
    int j = i & 7;
    int lane = (i >> 3) & 63;
    int ks = (i >> 9) & 1;
    int ct = (i >> 10) & 1;
    int e = i >> 11;
    int h = ks * 32 + (lane >> 4) * 8 + j;
    int k = ct * 16 + (lane & 15);
    Bpack2[i] = f2b(We1[(e * 64 + h) * 32 + k]);
  } else if (gid < 251904) {
    int i = gid - 245760;           // 0..6143
    int j = i & 7;
    int lane = (i >> 3) & 63;
    int u = i >> 9;                 // 0..11
    int k = (lane >> 4) * 8 + j;    // hidden index 0..31
    int col = lane & 15;
    float v = 0.f;
    if (col < 8) {
      v = (u < 8) ? Wg0b[(u * 32 + k) * 8 + col]
                  : Wg1b[((u - 8) * 32 + k) * 8 + col];
    }
    Bpack3[i] = f2b(v);
  }
}

// ---------------- fused kernel ----------------
// 2048 blocks x 512 threads, 32 rows/block.  LDS = 80128 B -> 2 blocks/CU.
//
// MFMA conventions (16x16x32 bf16, verified by stage-1 GEMM):
//   A-frag: lane l supplies A[row=l&15][k=(l>>4)*8+j]
//   B-frag: lane l supplies B[k=(l>>4)*8+j][col=l&15]
//   C/D  : lane l holds  D[row=(l>>4)*4+reg][col=l&15]
__global__ __launch_bounds__(THREADS, 4) void fused_kernel(
    const float* __restrict__ x,
    const unsigned short* __restrict__ Bpack,
    const float* __restrict__ bcat,
    const unsigned short* __restrict__ Bpack2,
    const unsigned short* __restrict__ Bpack3,
    const float* __restrict__ be1,
    const float* __restrict__ bg0b,
    const float* __restrict__ bg1b,
    float* __restrict__ out)
{
  __shared__ __align__(16) struct {
    union {
      struct {
        unsigned short xt[32 * 256];     // x tile bf16 swizzled (P1..P2)      16384 B
        unsigned short YgA[12 * 32 * 32];// gate hidden A-frags (epi..P3)      24576 B
      } a;
      unsigned short x1A[8 * 32 * 64];   // x1 A-frags for e1 (P4..P5)         32768 B
    } U;                                  // 40960 B
    union {
      unsigned short e0B[16 * 1032];     // e0 B-frags, pair-stride 1032 els   33024 B
      unsigned short e1buf[32 * 274];    // e1 bf16 (P5..P6)                   17536 B
    } A2;
    unsigned short g0L[32 * 64];         // g0 probs bf16 [b][g*8+e]            4096 B
    unsigned short g1L[32 * 32];         // g1 probs bf16 [b][t*8+e]            2048 B
  } S;                                    // total 80128 B

  const int tid = threadIdx.x;
  const int bid = blockIdx.x;
  const int lane = tid & 63;
  const int wave = tid >> 6;
  const int lr = lane & 15;
  const int lq = lane >> 4;

  // ---- P1: x tile (32x256 fp32) -> LDS bf16, XOR-swizzled ----
  {
    const float4* xg = (const float4*)(x + (size_t)bid * 32 * 256);
    char* xb = (char*)S.U.a.xt;
#pragma unroll
    for (int i = 0; i < 4; ++i) {
      int idx = tid + i * THREADS;          // float4 index 0..2047
      float4 f = xg[idx];
      int row = idx >> 6;
      unsigned int boff = (unsigned int)(idx & 63) * 8;
      unsigned int u0 = ((unsigned int)f2b(f.y) << 16) | f2b(f.x);
      unsigned int u1 = ((unsigned int)f2b(f.w) << 16) | f2b(f.z);
      unsigned int addr = ((unsigned int)row * 512 + boff) ^ (((unsigned int)(row & 7)) << 4);
      *(uint2*)(xb + addr) = make_uint2(u0, u1);
    }
  }
  __syncthreads();

  // ---- P2: stage-1 GEMM  [32x896] = relu(x @ Wcat + bcat) ----
  {
    float bias_r[7];
#pragma unroll
    for (int ng = 0; ng < 7; ++ng) bias_r[ng] = bcat[(wave * 7 + ng) * 16 + lr];

    f32x4 acc[2][7];
#pragma unroll
    for (int mt = 0; mt < 2; ++mt)
#pragma unroll
      for (int ng = 0; ng < 7; ++ng) acc[mt][ng] = {0.f, 0.f, 0.f, 0.f};

    const char* xb = (const char*)S.U.a.xt;
    const unsigned int sw = ((unsigned int)(lr & 7)) << 4;
    const unsigned int a0base = (unsigned int)lr * 512;
    const unsigned int a1base = (unsigned int)(16 + lr) * 512;
    const unsigned short* bp = Bpack + (size_t)(wave * 7) * 4096 + (size_t)lane * 8;

    __builtin_amdgcn_s_setprio(1);
#pragma unroll
    for (int ks = 0; ks < 8; ++ks) {
      unsigned int ko = (unsigned int)ks * 64 + (unsigned int)lq * 16;
      short8 a0 = *(const short8*)(xb + ((a0base + ko) ^ sw));
      short8 a1 = *(const short8*)(xb + ((a1base + ko) ^ sw));
#pragma unroll
      for (int ng = 0; ng < 7; ++ng) {
        short8 b = *(const short8*)(bp + (size_t)(ng * 8 + ks) * 512);
        acc[0][ng] = __builtin_amdgcn_mfma_f32_16x16x32_bf16(a0, b, acc[0][ng], 0, 0, 0);
        acc[1][ng] = __builtin_amdgcn_mfma_f32_16x16x32_bf16(a1, b, acc[1][ng], 0, 0, 0);
      }
    }
    __builtin_amdgcn_s_setprio(0);

    // epilogue: bias+relu.
    //  e0 cols -> e0B in combine-B-frag order: element e0[b][e][h]
    //    (p=b>>1, bi=b&1, n=h>>4, hcol=h&15) at el = p*1032 + n*256 + (bi*16+hcol)*8 + e
    //  gate cols -> YgA[u][row][k] A-frags, swizzled chunk kq^s2f(row)
#pragma unroll
    for (int ng = 0; ng < 7; ++ng) {
      int gcol = wave * 7 + ng;
      float bias = bias_r[ng];
      if (gcol < 32) {
        int e = gcol >> 2;
        int n = gcol & 3;
        int base_el = n * 256 + lr * 8 + e;
#pragma unroll
        for (int mt = 0; mt < 2; ++mt) {
#pragma unroll
          for (int rg = 0; rg < 4; ++rg) {
            int b = mt * 16 + lq * 4 + rg;
            float v = acc[mt][ng][rg] + bias;
            S.A2.e0B[(b >> 1) * 1032 + (b & 1) * 128 + base_el] = f2b(v > 0.f ? v : 0.f);
          }
        }
      } else {
        int c2 = gcol - 32;              // 0..23
        int u = c2 >> 1;
        int h = (c2 & 1) * 16 + lr;      // 0..31
        int kqw = h >> 3;
        int jw = h & 7;
#pragma unroll
        for (int mt = 0; mt < 2; ++mt) {
#pragma unroll
          for (int rg = 0; rg < 4; ++rg) {
            int row = mt * 16 + lq * 4 + rg;
            float v = acc[mt][ng][rg] + bias;
            S.U.a.YgA[u * 1024 + row * 32 + ((kqw ^ (int)s2f(row)) << 3) + jw] =
                f2b(v > 0.f ? v : 0.f);
          }
        }
      }
    }
  }
  __syncthreads();

  // ---- P3: gate logits via MFMA + cross-lane softmax ----
  // item id = u*2 + mt; wave handles ids 3w..3w+2 (24 items total)
  {
#pragma unroll
    for (int i = 0; i < 3; ++i) {
      int id = wave * 3 + i;
      int u = id >> 1;
      int mtq = id & 1;
      int row = lr + mtq * 16;           // batch row of this A row
      const char* yb = (const char*)S.U.a.YgA;
      short8 af = *(const short8*)(yb + u * 2048 + row * 64 +
                                   ((((unsigned int)lq) ^ s2f(row)) << 4));
      short8 bf = *(const short8*)(Bpack3 + (size_t)(u * 64 + lane) * 8);
      f32x4 dl = {0.f, 0.f, 0.f, 0.f};
      dl = __builtin_amdgcn_mfma_f32_16x16x32_bf16(af, bf, dl, 0, 0, 0);

      int col = lr;
      float bias = 0.f;
      if (col < 8) bias = (u < 8) ? bg0b[u * 8 + col] : bg1b[(u - 8) * 8 + col];
#pragma unroll
      for (int reg = 0; reg < 4; ++reg) {
        float lg = dl[reg] + bias;
        float m = lg;
        m = fmaxf(m, __shfl_xor(m, 1));
        m = fmaxf(m, __shfl_xor(m, 2));
        m = fmaxf(m, __shfl_xor(m, 4));
        float ex = __expf(lg - m);
        float s = ex;
        s += __shfl_xor(s, 1);
        s += __shfl_xor(s, 2);
        s += __shfl_xor(s, 4);
        float pv = ex / s;
        if (col < 8) {
          int b = mtq * 16 + lq * 4 + reg;
          if (u < 8) S.g0L[b * 64 + u * 8 + col] = f2b(pv);
          else       S.g1L[b * 32 + (u - 8) * 8 + col] = f2b(pv);
        }
      }
    }
  }
  __syncthreads();

  // ---- P4: x1 = g0 @ e0 via block-diagonal MFMA ----
  // pair p (rows 2p,2p+1): A(16x32): A[(bi*8+g)][bi'*8+e] = (bi==bi') g0[2p+bi][g][e]
  // B = e0B[p][n];  D[row=(bi*8+g)][col=hcol] = x1[2p+bi][g][n*16+hcol]
  {
    f32x4 xacc[2][4];
#pragma unroll
    for (int pi = 0; pi < 2; ++pi)
#pragma unroll
      for (int n = 0; n < 4; ++n) xacc[pi][n] = {0.f, 0.f, 0.f, 0.f};

    const short8 zero8 = {0, 0, 0, 0, 0, 0, 0, 0};
    const char* e0b = (const char*)S.A2.e0B;
#pragma unroll
    for (int pi = 0; pi < 2; ++pi) {
      int p = wave * 2 + pi;
      int kqh = lq & 1;
      int rtop = lr >> 3;
      int g = lane & 7;
      short8 ga = *(const short8*)&S.g0L[(2 * p + kqh) * 64 + g * 8];
      bool sel = (lane < 32) && (rtop == kqh);
      ga = sel ? ga : zero8;
#pragma unroll
      for (int n = 0; n < 4; ++n) {
        short8 bb = *(const short8*)(e0b + p * 2064 + n * 512 + (lane & 31) * 16);
        xacc[pi][n] = __builtin_amdgcn_mfma_f32_16x16x32_bf16(ga, bb, xacc[pi][n], 0, 0, 0);
      }
    }
    // write x1 -> x1A (bf16 A-frags for e1): element (E=g, b, h) at
    // byte = E*4096 + b*128 + (((h>>3)^(b&7))<<4) + (h&7)*2
    char* x1b = (char*)S.U.x1A;
#pragma unroll
    for (int pi = 0; pi < 2; ++pi) {
      int p = wave * 2 + pi;
#pragma unroll
      for (int n = 0; n < 4; ++n) {
#pragma unroll
        for (int reg = 0; reg < 4; ++reg) {
          int row16 = lq * 4 + reg;
          int bi = row16 >> 3, g = row16 & 7;
          int b = 2 * p + bi;
          int h = n * 16 + lr;
          *(unsigned short*)(x1b + g * 4096 + b * 128 +
                             ((((unsigned int)(h >> 3)) ^ ((unsigned int)b & 7)) << 4) +
                             (h & 7) * 2) = f2b(xacc[pi][n][reg]);
        }
      }
    }
  }
  __syncthreads();

  // ---- P5: e1 = relu(x1 @ We1 + be1) via MFMA.  wave w = expert w ----
  // Bpack2 fragments loaded HERE (not held persistently) -- avoids cross-phase
  // register pressure; round-6's persistent copy caused scratch spills
  // (WRITE_SIZE 33->82 MB).  The 4x16B L2 loads hide under P5's MFMAs.
  {
    const int w = wave;
    short8 b2r[4];
#pragma unroll
    for (int ct = 0; ct < 2; ++ct)
#pragma unroll
      for (int k2 = 0; k2 < 2; ++k2)
        b2r[ct * 2 + k2] =
            *(const short8*)(Bpack2 + (size_t)(w * 4 + ct * 2 + k2) * 512 + lane * 8);

    f32x4 eacc[2][2];
#pragma unroll
    for (int mt = 0; mt < 2; ++mt)
#pragma unroll
      for (int ct = 0; ct < 2; ++ct) eacc[mt][ct] = {0.f, 0.f, 0.f, 0.f};

    const char* x1b = (const char*)S.U.x1A;
#pragma unroll
    for (int ks = 0; ks < 2; ++ks) {
#pragma unroll
      for (int mt = 0; mt < 2; ++mt) {
        int bp_ = lr + 16 * mt;
        short8 a = *(const short8*)(x1b + w * 4096 + bp_ * 128 +
                    ((((unsigned int)(ks * 4 + lq)) ^ ((unsigned int)bp_ & 7)) << 4));
        eacc[mt][0] = __builtin_amdgcn_mfma_f32_16x16x32_bf16(a, b2r[0 * 2 + ks], eacc[mt][0], 0, 0, 0);
        eacc[mt][1] = __builtin_amdgcn_mfma_f32_16x16x32_bf16(a, b2r[1 * 2 + ks], eacc[mt][1], 0, 0, 0);
      }
    }
    unsigned short* e1buf = S.A2.e1buf;
#pragma unroll
    for (int ct = 0; ct < 2; ++ct) {
      int k = ct * 16 + lr;
      float bias = be1[w * 32 + k];
#pragma unroll
      for (int mt = 0; mt < 2; ++mt) {
#pragma unroll
        for (int rg = 0; rg < 4; ++rg) {
          int row = mt * 16 + lq * 4 + rg;
          float v = eacc[mt][ct][rg] + bias;
          e1buf[row * 274 + w * 34 + k] = f2b(v > 0.f ? v : 0.f);
        }
      }
    }
  }
  __syncthreads();

  // ---- P6: out[t][k] = sum_e g1[t][e]*e1[e][k].  thread (r,j) owns k={2j,2j+1} ----
  {
    const int r = tid >> 4;
    const int j = tid & 15;
    const unsigned short* e1buf = S.A2.e1buf;
    short8 gvt[4];                     // one short8 per task t (8 expert probs)
#pragma unroll
    for (int t = 0; t < 4; ++t)
      gvt[t] = *(const short8*)&S.g1L[r * 32 + t * 8];
    float o0[4], o1[4];
#pragma unroll
    for (int t = 0; t < 4; ++t) { o0[t] = 0.f; o1[t] = 0.f; }
#pragma unroll
    for (int q = 0; q < 8; ++q) {
      unsigned int uu = *(const unsigned int*)&e1buf[r * 274 + q * 34 + j * 2];
      float ev0, ev1;
      unpack2(uu, ev0, ev1);
#pragma unroll
      for (int t = 0; t < 4; ++t) {
        float gt = b2f((unsigned short)gvt[t][q]);
        o0[t] += gt * ev0;
        o1[t] += gt * ev1;
      }
    }
    float* op = out + ((size_t)bid * 32 + r) * 128 + j * 2;
#pragma unroll
    for (int t = 0; t < 4; ++t) {
      *(float2*)(op + t * 32) = make_float2(o0[t], o1[t]);
    }
  }
}

extern "C" void kernel_launch(void* const* d_in, const int* in_sizes, int n_in,
                              void* d_out, int out_size, void* d_ws, size_t ws_size,
                              hipStream_t stream) {
  const float* x    = (const float*)d_in[0];
  const float* We0  = (const float*)d_in[1];
  const float* be0  = (const float*)d_in[2];
  const float* We1  = (const float*)d_in[3];
  const float* be1  = (const float*)d_in[4];
  const float* Wg0a = (const float*)d_in[5];
  const float* bg0a = (const float*)d_in[6];
  const float* Wg0b = (const float*)d_in[7];
  const float* bg0b = (const float*)d_in[8];
  const float* Wg1a = (const float*)d_in[9];
  const float* bg1a = (const float*)d_in[10];
  const float* Wg1b = (const float*)d_in[11];
  const float* bg1b = (const float*)d_in[12];

  unsigned short* Bpack  = (unsigned short*)d_ws;
  float*          bcat   = (float*)((char*)d_ws + 458752);
  unsigned short* Bpack2 = (unsigned short*)((char*)d_ws + 462336);
  unsigned short* Bpack3 = (unsigned short*)((char*)d_ws + 495104);

  pack_kernel<<<492, 512, 0, stream>>>(We0, Wg0a, Wg1a, be0, bg0a, bg1a, We1,
                                       Wg0b, Wg1b, Bpack, bcat, Bpack2, Bpack3);
  fused_kernel<<<2048, 512, 0, stream>>>(x, Bpack, bcat, Bpack2, Bpack3, be1,
                                         bg0b, bg1b, (float*)d_out);
}

// Round 8
// 94.341 us; speedup vs baseline: 1.1644x; 1.1417x over previous
//
#include <hip/hip_runtime.h>

typedef __attribute__((ext_vector_type(8))) short short8;
typedef __attribute__((ext_vector_type(4))) float f32x4;

#define THREADS 512

__device__ __forceinline__ float b2f(unsigned short u) {
  return __uint_as_float(((unsigned int)u) << 16);
}
__device__ __forceinline__ unsigned short f2b(float f) {
  unsigned int i = __float_as_uint(f);
  unsigned int r = (i + 0x7fffu + ((i >> 16) & 1u)) >> 16;
  return (unsigned short)r;
}
__device__ __forceinline__ void unpack2(unsigned int u, float& a, float& b) {
  a = __uint_as_float(u << 16);
  b = __uint_as_float(u & 0xffff0000u);
}
// row-dependent 2-bit swizzle for 64B-row A-fragment tiles
__device__ __forceinline__ unsigned int s2f(unsigned int r) {
  return (r + (r >> 2)) & 3u;
}

// ---------------- pack kernel ----------------
// Bpack  (stage-1 B): [((g*8+ks)*64+lane)*8+j] = Wcat[d=ks*32+(lane>>4)*8+j][col=g*16+(lane&15)]
//   Wcat cols: [0,512)=We0 (col=e*64+h), [512,768)=Wg0a, [768,896)=Wg1a
// Bpack2 (e1 B): [(((e*2+ct)*2+ks)*64+lane)*8+j] = We1[e][h=ks*32+(lane>>4)*8+j][k=ct*16+(lane&15)]
// Bpack3 (gate B): [(u*64+lane)*8+j] = col<8 ? Wg[u][k=(lane>>4)*8+j][col] : 0   (col=lane&15)
__global__ void pack_kernel(const float* __restrict__ We0,
                            const float* __restrict__ Wg0a,
                            const float* __restrict__ Wg1a,
                            const float* __restrict__ be0,
                            const float* __restrict__ bg0a,
                            const float* __restrict__ bg1a,
                            const float* __restrict__ We1,
                            const float* __restrict__ Wg0b,
                            const float* __restrict__ Wg1b,
                            unsigned short* __restrict__ Bpack,
                            float* __restrict__ bcat,
                            unsigned short* __restrict__ Bpack2,
                            unsigned short* __restrict__ Bpack3) {
  int gid = blockIdx.x * blockDim.x + threadIdx.x;
  if (gid < 229376) {
    int j = gid & 7;
    int lane = (gid >> 3) & 63;
    int ks = (gid >> 9) & 7;
    int g = gid >> 12;
    int d = ks * 32 + (lane >> 4) * 8 + j;
    int col = g * 16 + (lane & 15);
    float v;
    if (col < 512) {
      v = We0[((col >> 6) * 256 + d) * 64 + (col & 63)];
    } else if (col < 768) {
      int c = col - 512;
      v = Wg0a[((c >> 5) * 256 + d) * 32 + (c & 31)];
    } else {
      int c = col - 768;
      v = Wg1a[((c >> 5) * 256 + d) * 32 + (c & 31)];
    }
    Bpack[gid] = f2b(v);
    if (gid < 896) {
      float bv;
      if (gid < 512) bv = be0[gid];
      else if (gid < 768) bv = bg0a[gid - 512];
      else bv = bg1a[gid - 768];
      bcat[gid] = bv;
    }
  } else if (gid < 245760) {
    int i = gid - 229376;           // 0..16383
    int j = i & 7;
    int lane = (i >> 3) & 63;
    int ks = (i >> 9) & 1;
    int ct = (i >> 10) & 1;
    int e = i >> 11;
    int h = ks * 32 + (lane >> 4) * 8 + j;
    int k = ct * 16 + (lane & 15);
    Bpack2[i] = f2b(We1[(e * 64 + h) * 32 + k]);
  } else if (gid < 251904) {
    int i = gid - 245760;           // 0..6143
    int j = i & 7;
    int lane = (i >> 3) & 63;
    int u = i >> 9;                 // 0..11
    int k = (lane >> 4) * 8 + j;    // hidden index 0..31
    int col = lane & 15;
    float v = 0.f;
    if (col < 8) {
      v = (u < 8) ? Wg0b[(u * 32 + k) * 8 + col]
                  : Wg1b[((u - 8) * 32 + k) * 8 + col];
    }
    Bpack3[i] = f2b(v);
  }
}

// ---------------- fused kernel ----------------
// 2048 blocks x 512 threads, 32 rows/block.  LDS = 80128 B -> 2 blocks/CU.
//
// MFMA conventions (16x16x32 bf16, verified by stage-1 GEMM):
//   A-frag: lane l supplies A[row=l&15][k=(l>>4)*8+j]
//   B-frag: lane l supplies B[k=(l>>4)*8+j][col=l&15]
//   C/D  : lane l holds  D[row=(l>>4)*4+reg][col=l&15]
__global__ __launch_bounds__(THREADS, 4) void fused_kernel(
    const float* __restrict__ x,
    const unsigned short* __restrict__ Bpack,
    const float* __restrict__ bcat,
    const unsigned short* __restrict__ Bpack2,
    const unsigned short* __restrict__ Bpack3,
    const float* __restrict__ be1,
    const float* __restrict__ bg0b,
    const float* __restrict__ bg1b,
    float* __restrict__ out)
{
  __shared__ __align__(16) struct {
    union {
      struct {
        unsigned short xt[32 * 256];     // x tile bf16 swizzled (P1..P2)      16384 B
        unsigned short YgA[12 * 32 * 32];// gate hidden A-frags (epi..P3)      24576 B
      } a;
      unsigned short x1A[8 * 32 * 64];   // x1 A-frags for e1 (P4..P5)         32768 B
    } U;                                  // 40960 B
    union {
      unsigned short e0B[16 * 1032];     // e0 B-frags, pair-stride 1032 els   33024 B
      unsigned short e1buf[32 * 274];    // e1 bf16 (P5..P6)                   17536 B
    } A2;
    unsigned short g0L[32 * 64];         // g0 probs bf16 [b][g*8+e]            4096 B
    unsigned short g1L[32 * 32];         // g1 probs bf16 [b][t*8+e]            2048 B
  } S;                                    // total 80128 B

  const int tid = threadIdx.x;
  const int bid = blockIdx.x;
  const int lane = tid & 63;
  const int wave = tid >> 6;
  const int lr = lane & 15;
  const int lq = lane >> 4;

  // ---- P1: x tile (32x256 fp32) -> LDS bf16, XOR-swizzled ----
  {
    const float4* xg = (const float4*)(x + (size_t)bid * 32 * 256);
    char* xb = (char*)S.U.a.xt;
#pragma unroll
    for (int i = 0; i < 4; ++i) {
      int idx = tid + i * THREADS;          // float4 index 0..2047
      float4 f = xg[idx];
      int row = idx >> 6;
      unsigned int boff = (unsigned int)(idx & 63) * 8;
      unsigned int u0 = ((unsigned int)f2b(f.y) << 16) | f2b(f.x);
      unsigned int u1 = ((unsigned int)f2b(f.w) << 16) | f2b(f.z);
      unsigned int addr = ((unsigned int)row * 512 + boff) ^ (((unsigned int)(row & 7)) << 4);
      *(uint2*)(xb + addr) = make_uint2(u0, u1);
    }
  }
  __syncthreads();
  __builtin_amdgcn_sched_barrier(0);

  // ---- P2: stage-1 GEMM  [32x896] = relu(x @ Wcat + bcat) ----
  {
    f32x4 acc[2][7];
#pragma unroll
    for (int mt = 0; mt < 2; ++mt)
#pragma unroll
      for (int ng = 0; ng < 7; ++ng) acc[mt][ng] = {0.f, 0.f, 0.f, 0.f};

    const char* xb = (const char*)S.U.a.xt;
    const unsigned int sw = ((unsigned int)(lr & 7)) << 4;
    const unsigned int a0base = (unsigned int)lr * 512;
    const unsigned int a1base = (unsigned int)(16 + lr) * 512;
    const unsigned short* bp = Bpack + (size_t)(wave * 7) * 4096 + (size_t)lane * 8;

    __builtin_amdgcn_s_setprio(1);
#pragma unroll
    for (int ks = 0; ks < 8; ++ks) {
      unsigned int ko = (unsigned int)ks * 64 + (unsigned int)lq * 16;
      short8 a0 = *(const short8*)(xb + ((a0base + ko) ^ sw));
      short8 a1 = *(const short8*)(xb + ((a1base + ko) ^ sw));
#pragma unroll
      for (int ng = 0; ng < 7; ++ng) {
        short8 b = *(const short8*)(bp + (size_t)(ng * 8 + ks) * 512);
        acc[0][ng] = __builtin_amdgcn_mfma_f32_16x16x32_bf16(a0, b, acc[0][ng], 0, 0, 0);
        acc[1][ng] = __builtin_amdgcn_mfma_f32_16x16x32_bf16(a1, b, acc[1][ng], 0, 0, 0);
      }
    }
    __builtin_amdgcn_s_setprio(0);
    __builtin_amdgcn_sched_barrier(0);

    // epilogue: bias+relu.  bias loaded HERE (not prefetched across the MFMA
    // loop -- keeps arch-VGPR liveness off the 56-AGPR pressure peak).
    //  e0 cols -> e0B in combine-B-frag order: element e0[b][e][h]
    //    (p=b>>1, bi=b&1, n=h>>4, hcol=h&15) at el = p*1032 + n*256 + (bi*16+hcol)*8 + e
    //  gate cols -> YgA[u][row][k] A-frags, swizzled chunk kq^s2f(row)
#pragma unroll
    for (int ng = 0; ng < 7; ++ng) {
      int gcol = wave * 7 + ng;
      float bias = bcat[gcol * 16 + lr];
      if (gcol < 32) {
        int e = gcol >> 2;
        int n = gcol & 3;
        int base_el = n * 256 + lr * 8 + e;
#pragma unroll
        for (int mt = 0; mt < 2; ++mt) {
#pragma unroll
          for (int rg = 0; rg < 4; ++rg) {
            int b = mt * 16 + lq * 4 + rg;
            float v = acc[mt][ng][rg] + bias;
            S.A2.e0B[(b >> 1) * 1032 + (b & 1) * 128 + base_el] = f2b(v > 0.f ? v : 0.f);
          }
        }
      } else {
        int c2 = gcol - 32;              // 0..23
        int u = c2 >> 1;
        int h = (c2 & 1) * 16 + lr;      // 0..31
        int kqw = h >> 3;
        int jw = h & 7;
#pragma unroll
        for (int mt = 0; mt < 2; ++mt) {
#pragma unroll
          for (int rg = 0; rg < 4; ++rg) {
            int row = mt * 16 + lq * 4 + rg;
            float v = acc[mt][ng][rg] + bias;
            S.U.a.YgA[u * 1024 + row * 32 + ((kqw ^ (int)s2f(row)) << 3) + jw] =
                f2b(v > 0.f ? v : 0.f);
          }
        }
      }
    }
  }
  __syncthreads();
  __builtin_amdgcn_sched_barrier(0);

  // ---- P3: gate logits via MFMA + cross-lane softmax ----
  // item id = u*2 + mt; wave handles ids 3w..3w+2 (24 items total)
  {
#pragma unroll
    for (int i = 0; i < 3; ++i) {
      int id = wave * 3 + i;
      int u = id >> 1;
      int mtq = id & 1;
      int row = lr + mtq * 16;           // batch row of this A row
      const char* yb = (const char*)S.U.a.YgA;
      short8 af = *(const short8*)(yb + u * 2048 + row * 64 +
                                   ((((unsigned int)lq) ^ s2f(row)) << 4));
      short8 bf = *(const short8*)(Bpack3 + (size_t)(u * 64 + lane) * 8);
      f32x4 dl = {0.f, 0.f, 0.f, 0.f};
      dl = __builtin_amdgcn_mfma_f32_16x16x32_bf16(af, bf, dl, 0, 0, 0);

      int col = lr;
      float bias = 0.f;
      if (col < 8) bias = (u < 8) ? bg0b[u * 8 + col] : bg1b[(u - 8) * 8 + col];
#pragma unroll
      for (int reg = 0; reg < 4; ++reg) {
        float lg = dl[reg] + bias;
        float m = lg;
        m = fmaxf(m, __shfl_xor(m, 1));
        m = fmaxf(m, __shfl_xor(m, 2));
        m = fmaxf(m, __shfl_xor(m, 4));
        float ex = __expf(lg - m);
        float s = ex;
        s += __shfl_xor(s, 1);
        s += __shfl_xor(s, 2);
        s += __shfl_xor(s, 4);
        float pv = ex / s;
        if (col < 8) {
          int b = mtq * 16 + lq * 4 + reg;
          if (u < 8) S.g0L[b * 64 + u * 8 + col] = f2b(pv);
          else       S.g1L[b * 32 + (u - 8) * 8 + col] = f2b(pv);
        }
      }
    }
  }
  __syncthreads();
  __builtin_amdgcn_sched_barrier(0);

  // ---- P4: x1 = g0 @ e0 via block-diagonal MFMA ----
  // pair p (rows 2p,2p+1): A(16x32): A[(bi*8+g)][bi'*8+e] = (bi==bi') g0[2p+bi][g][e]
  // B = e0B[p][n];  D[row=(bi*8+g)][col=hcol] = x1[2p+bi][g][n*16+hcol]
  {
    f32x4 xacc[2][4];
#pragma unroll
    for (int pi = 0; pi < 2; ++pi)
#pragma unroll
      for (int n = 0; n < 4; ++n) xacc[pi][n] = {0.f, 0.f, 0.f, 0.f};

    const short8 zero8 = {0, 0, 0, 0, 0, 0, 0, 0};
    const char* e0b = (const char*)S.A2.e0B;
#pragma unroll
    for (int pi = 0; pi < 2; ++pi) {
      int p = wave * 2 + pi;
      int kqh = lq & 1;
      int rtop = lr >> 3;
      int g = lane & 7;
      short8 ga = *(const short8*)&S.g0L[(2 * p + kqh) * 64 + g * 8];
      bool sel = (lane < 32) && (rtop == kqh);
      ga = sel ? ga : zero8;
#pragma unroll
      for (int n = 0; n < 4; ++n) {
        short8 bb = *(const short8*)(e0b + p * 2064 + n * 512 + (lane & 31) * 16);
        xacc[pi][n] = __builtin_amdgcn_mfma_f32_16x16x32_bf16(ga, bb, xacc[pi][n], 0, 0, 0);
      }
    }
    // write x1 -> x1A (bf16 A-frags for e1): element (E=g, b, h) at
    // byte = E*4096 + b*128 + (((h>>3)^(b&7))<<4) + (h&7)*2
    char* x1b = (char*)S.U.x1A;
#pragma unroll
    for (int pi = 0; pi < 2; ++pi) {
      int p = wave * 2 + pi;
#pragma unroll
      for (int n = 0; n < 4; ++n) {
#pragma unroll
        for (int reg = 0; reg < 4; ++reg) {
          int row16 = lq * 4 + reg;
          int bi = row16 >> 3, g = row16 & 7;
          int b = 2 * p + bi;
          int h = n * 16 + lr;
          *(unsigned short*)(x1b + g * 4096 + b * 128 +
                             ((((unsigned int)(h >> 3)) ^ ((unsigned int)b & 7)) << 4) +
                             (h & 7) * 2) = f2b(xacc[pi][n][reg]);
        }
      }
    }
  }
  __syncthreads();
  __builtin_amdgcn_sched_barrier(0);

  // ---- P5: e1 = relu(x1 @ We1 + be1) via MFMA.  wave w = expert w ----
  // B fragments loaded per-ks (max 8 dwords live), from L2-resident Bpack2.
  {
    const int w = wave;
    f32x4 eacc[2][2];
#pragma unroll
    for (int mt = 0; mt < 2; ++mt)
#pragma unroll
      for (int ct = 0; ct < 2; ++ct) eacc[mt][ct] = {0.f, 0.f, 0.f, 0.f};

    const char* x1b = (const char*)S.U.x1A;
#pragma unroll
    for (int ks = 0; ks < 2; ++ks) {
      short8 b0 = *(const short8*)(Bpack2 + (size_t)(w * 4 + 0 * 2 + ks) * 512 + lane * 8);
      short8 b1 = *(const short8*)(Bpack2 + (size_t)(w * 4 + 1 * 2 + ks) * 512 + lane * 8);
#pragma unroll
      for (int mt = 0; mt < 2; ++mt) {
        int bp_ = lr + 16 * mt;
        short8 a = *(const short8*)(x1b + w * 4096 + bp_ * 128 +
                    ((((unsigned int)(ks * 4 + lq)) ^ ((unsigned int)bp_ & 7)) << 4));
        eacc[mt][0] = __builtin_amdgcn_mfma_f32_16x16x32_bf16(a, b0, eacc[mt][0], 0, 0, 0);
        eacc[mt][1] = __builtin_amdgcn_mfma_f32_16x16x32_bf16(a, b1, eacc[mt][1], 0, 0, 0);
      }
    }
    unsigned short* e1buf = S.A2.e1buf;
#pragma unroll
    for (int ct = 0; ct < 2; ++ct) {
      int k = ct * 16 + lr;
      float bias = be1[w * 32 + k];
#pragma unroll
      for (int mt = 0; mt < 2; ++mt) {
#pragma unroll
        for (int rg = 0; rg < 4; ++rg) {
          int row = mt * 16 + lq * 4 + rg;
          float v = eacc[mt][ct][rg] + bias;
          e1buf[row * 274 + w * 34 + k] = f2b(v > 0.f ? v : 0.f);
        }
      }
    }
  }
  __syncthreads();
  __builtin_amdgcn_sched_barrier(0);

  // ---- P6: out[t][k] = sum_e g1[t][e]*e1[e][k].  thread (r,j) owns k={2j,2j+1}.
  //      Gate probs read as scalar LDS broadcasts at use (no gvt[] array). ----
  {
    const int r = tid >> 4;
    const int j = tid & 15;
    const unsigned short* e1buf = S.A2.e1buf;
    float o0[4], o1[4];
#pragma unroll
    for (int t = 0; t < 4; ++t) { o0[t] = 0.f; o1[t] = 0.f; }
#pragma unroll
    for (int q = 0; q < 8; ++q) {
      unsigned int uu = *(const unsigned int*)&e1buf[r * 274 + q * 34 + j * 2];
      float ev0, ev1;
      unpack2(uu, ev0, ev1);
#pragma unroll
      for (int t = 0; t < 4; ++t) {
        float gt = b2f(S.g1L[r * 32 + t * 8 + q]);
        o0[t] += gt * ev0;
        o1[t] += gt * ev1;
      }
    }
    float* op = out + ((size_t)bid * 32 + r) * 128 + j * 2;
#pragma unroll
    for (int t = 0; t < 4; ++t) {
      *(float2*)(op + t * 32) = make_float2(o0[t], o1[t]);
    }
  }
}

extern "C" void kernel_launch(void* const* d_in, const int* in_sizes, int n_in,
                              void* d_out, int out_size, void* d_ws, size_t ws_size,
                              hipStream_t stream) {
  const float* x    = (const float*)d_in[0];
  const float* We0  = (const float*)d_in[1];
  const float* be0  = (const float*)d_in[2];
  const float* We1  = (const float*)d_in[3];
  const float* be1  = (const float*)d_in[4];
  const float* Wg0a = (const float*)d_in[5];
  const float* bg0a = (const float*)d_in[6];
  const float* Wg0b = (const float*)d_in[7];
  const float* bg0b = (const float*)d_in[8];
  const float* Wg1a = (const float*)d_in[9];
  const float* bg1a = (const float*)d_in[10];
  const float* Wg1b = (const float*)d_in[11];
  const float* bg1b = (const float*)d_in[12];

  unsigned short* Bpack  = (unsigned short*)d_ws;
  float*          bcat   = (float*)((char*)d_ws + 458752);
  unsigned short* Bpack2 = (unsigned short*)((char*)d_ws + 462336);
  unsigned short* Bpack3 = (unsigned short*)((char*)d_ws + 495104);

  pack_kernel<<<492, 512, 0, stream>>>(We0, Wg0a, Wg1a, be0, bg0a, bg1a, We1,
                                       Wg0b, Wg1b, Bpack, bcat, Bpack2, Bpack3);
  fused_kernel<<<2048, 512, 0, stream>>>(x, Bpack, bcat, Bpack2, Bpack3, be1,
                                         bg0b, bg1b, (float*)d_out);
}

// Round 9
// 91.969 us; speedup vs baseline: 1.1944x; 1.0258x over previous
//
#include <hip/hip_runtime.h>

typedef __attribute__((ext_vector_type(8))) short short8;
typedef __attribute__((ext_vector_type(4))) float f32x4;

#define THREADS 512

__device__ __forceinline__ float b2f(unsigned short u) {
  return __uint_as_float(((unsigned int)u) << 16);
}
__device__ __forceinline__ unsigned short f2b(float f) {
  unsigned int i = __float_as_uint(f);
  unsigned int r = (i + 0x7fffu + ((i >> 16) & 1u)) >> 16;
  return (unsigned short)r;
}
__device__ __forceinline__ unsigned int cvt_pk_bf16(float lo, float hi) {
  unsigned int r;
  asm volatile("v_cvt_pk_bf16_f32 %0, %1, %2" : "=v"(r) : "v"(lo), "v"(hi));
  return r;
}
__device__ __forceinline__ void unpack2(unsigned int u, float& a, float& b) {
  a = __uint_as_float(u << 16);
  b = __uint_as_float(u & 0xffff0000u);
}
// row-dependent 2-bit swizzle for 64B-row A-fragment tiles
__device__ __forceinline__ unsigned int s2f(unsigned int r) {
  return (r + (r >> 2)) & 3u;
}

// ---------------- pack kernel ----------------
// Bpack slot order (per-wave pair-friendly):
//   slot g_slot = w*7+ng ; gcol(w,ng):
//     ng<4 : pr = 2w+(ng>>1); gcol = 8*(pr>>2) + (pr&3) + (ng&1)*4   (e0 pairs e,e+1)
//     ng>=4: gcol = 32 + 3w + (ng-4)                                  (gate groups)
// Bpack[((g_slot*8+ks)*64+lane)*8+j] = Wcat[d=ks*32+(lane>>4)*8+j][col=gcol*16+(lane&15)]
//   Wcat cols: [0,512)=We0 (col=e*64+h), [512,768)=Wg0a, [768,896)=Wg1a
// Bpack2 (e1 B): [(((e*2+ct)*2+ks)*64+lane)*8+j] = We1[e][h=ks*32+(lane>>4)*8+j][k=ct*16+(lane&15)]
// Bpack3 (gate B): [(u*64+lane)*8+j] = col<8 ? Wg[u][k=(lane>>4)*8+j][col] : 0   (col=lane&15)
__global__ void pack_kernel(const float* __restrict__ We0,
                            const float* __restrict__ Wg0a,
                            const float* __restrict__ Wg1a,
                            const float* __restrict__ be0,
                            const float* __restrict__ bg0a,
                            const float* __restrict__ bg1a,
                            const float* __restrict__ We1,
                            const float* __restrict__ Wg0b,
                            const float* __restrict__ Wg1b,
                            unsigned short* __restrict__ Bpack,
                            float* __restrict__ bcat,
                            unsigned short* __restrict__ Bpack2,
                            unsigned short* __restrict__ Bpack3) {
  int gid = blockIdx.x * blockDim.x + threadIdx.x;
  if (gid < 229376) {
    int j = gid & 7;
    int lane = (gid >> 3) & 63;
    int ks = (gid >> 9) & 7;
    int g_slot = gid >> 12;
    int w = g_slot / 7;
    int ng = g_slot - w * 7;
    int gcol;
    if (ng < 4) {
      int pr = 2 * w + (ng >> 1);
      gcol = 8 * (pr >> 2) + (pr & 3) + (ng & 1) * 4;
    } else {
      gcol = 32 + 3 * w + (ng - 4);
    }
    int d = ks * 32 + (lane >> 4) * 8 + j;
    int col = gcol * 16 + (lane & 15);
    float v;
    if (col < 512) {
      v = We0[((col >> 6) * 256 + d) * 64 + (col & 63)];
    } else if (col < 768) {
      int c = col - 512;
      v = Wg0a[((c >> 5) * 256 + d) * 32 + (c & 31)];
    } else {
      int c = col - 768;
      v = Wg1a[((c >> 5) * 256 + d) * 32 + (c & 31)];
    }
    Bpack[gid] = f2b(v);
    if (gid < 896) {
      float bv;
      if (gid < 512) bv = be0[gid];
      else if (gid < 768) bv = bg0a[gid - 512];
      else bv = bg1a[gid - 768];
      bcat[gid] = bv;
    }
  } else if (gid < 245760) {
    int i = gid - 229376;           // 0..16383
    int j = i & 7;
    int lane = (i >> 3) & 63;
    int ks = (i >> 9) & 1;
    int ct = (i >> 10) & 1;
    int e = i >> 11;
    int h = ks * 32 + (lane >> 4) * 8 + j;
    int k = ct * 16 + (lane & 15);
    Bpack2[i] = f2b(We1[(e * 64 + h) * 32 + k]);
  } else if (gid < 251904) {
    int i = gid - 245760;           // 0..6143
    int j = i & 7;
    int lane = (i >> 3) & 63;
    int u = i >> 9;                 // 0..11
    int k = (lane >> 4) * 8 + j;    // hidden index 0..31
    int col = lane & 15;
    float v = 0.f;
    if (col < 8) {
      v = (u < 8) ? Wg0b[(u * 32 + k) * 8 + col]
                  : Wg1b[((u - 8) * 32 + k) * 8 + col];
    }
    Bpack3[i] = f2b(v);
  }
}

// ---------------- fused kernel ----------------
// 2048 blocks x 512 threads, 32 rows/block.  LDS = 80128 B -> 2 blocks/CU.
//
// MFMA conventions (16x16x32 bf16, verified by stage-1 GEMM):
//   A-frag: lane l supplies A[row=l&15][k=(l>>4)*8+j]
//   B-frag: lane l supplies B[k=(l>>4)*8+j][col=l&15]
//   C/D  : lane l holds  D[row=(l>>4)*4+reg][col=l&15]
__global__ __launch_bounds__(THREADS, 4) void fused_kernel(
    const float* __restrict__ x,
    const unsigned short* __restrict__ Bpack,
    const float* __restrict__ bcat,
    const unsigned short* __restrict__ Bpack2,
    const unsigned short* __restrict__ Bpack3,
    const float* __restrict__ be1,
    const float* __restrict__ bg0b,
    const float* __restrict__ bg1b,
    float* __restrict__ out)
{
  __shared__ __align__(16) struct {
    union {
      struct {
        unsigned short xt[32 * 256];     // x tile bf16 swizzled (P1..P2)      16384 B
        unsigned short YgA[12 * 32 * 32];// gate hidden A-frags (epi..P3)      24576 B
      } a;
      unsigned short x1A[8 * 32 * 64];   // x1 A-frags for e1 (P4..P5)         32768 B
    } U;                                  // 40960 B
    union {
      unsigned short e0B[16 * 1032];     // e0 B-frags, pair-stride 1032 els   33024 B
      unsigned short e1buf[32 * 274];    // e1 bf16 (P5..P6)                   17536 B
    } A2;
    unsigned short g0L[32 * 64];         // g0 probs bf16 [b][g*8+e]            4096 B
    unsigned short g1L[32 * 32];         // g1 probs bf16 [b][t*8+e]            2048 B
  } S;                                    // total 80128 B

  const int tid = threadIdx.x;
  const int bid = blockIdx.x;
  const int lane = tid & 63;
  const int wave = tid >> 6;
  const int lr = lane & 15;
  const int lq = lane >> 4;

  // ---- P1: x tile (32x256 fp32) -> LDS bf16, XOR-swizzled ----
  {
    const float4* xg = (const float4*)(x + (size_t)bid * 32 * 256);
    char* xb = (char*)S.U.a.xt;
#pragma unroll
    for (int i = 0; i < 4; ++i) {
      int idx = tid + i * THREADS;          // float4 index 0..2047
      float4 f = xg[idx];
      int row = idx >> 6;
      unsigned int boff = (unsigned int)(idx & 63) * 8;
      unsigned int u0 = cvt_pk_bf16(f.x, f.y);
      unsigned int u1 = cvt_pk_bf16(f.z, f.w);
      unsigned int addr = ((unsigned int)row * 512 + boff) ^ (((unsigned int)(row & 7)) << 4);
      *(uint2*)(xb + addr) = make_uint2(u0, u1);
    }
  }
  __syncthreads();
  __builtin_amdgcn_sched_barrier(0);

  // ---- P2: stage-1 GEMM  [32x896] = relu(x @ Wcat + bcat) ----
  {
    f32x4 acc[2][7];
#pragma unroll
    for (int mt = 0; mt < 2; ++mt)
#pragma unroll
      for (int ng = 0; ng < 7; ++ng) acc[mt][ng] = {0.f, 0.f, 0.f, 0.f};

    const char* xb = (const char*)S.U.a.xt;
    const unsigned int sw = ((unsigned int)(lr & 7)) << 4;
    const unsigned int a0base = (unsigned int)lr * 512;
    const unsigned int a1base = (unsigned int)(16 + lr) * 512;
    const unsigned short* bp = Bpack + (size_t)(wave * 7) * 4096 + (size_t)lane * 8;

    __builtin_amdgcn_s_setprio(1);
#pragma unroll
    for (int ks = 0; ks < 8; ++ks) {
      unsigned int ko = (unsigned int)ks * 64 + (unsigned int)lq * 16;
      short8 a0 = *(const short8*)(xb + ((a0base + ko) ^ sw));
      short8 a1 = *(const short8*)(xb + ((a1base + ko) ^ sw));
#pragma unroll
      for (int ng = 0; ng < 7; ++ng) {
        short8 b = *(const short8*)(bp + (size_t)(ng * 8 + ks) * 512);
        acc[0][ng] = __builtin_amdgcn_mfma_f32_16x16x32_bf16(a0, b, acc[0][ng], 0, 0, 0);
        acc[1][ng] = __builtin_amdgcn_mfma_f32_16x16x32_bf16(a1, b, acc[1][ng], 0, 0, 0);
      }
    }
    __builtin_amdgcn_s_setprio(0);
    __builtin_amdgcn_sched_barrier(0);

    // epilogue: bias+relu.
    //  slots 0..3 = two e0 (gcol, gcol+4) pairs -> paired cvt_pk + b32 stores
    //  slots 4..6 = gate groups -> YgA u16 scatter (unchanged)
#pragma unroll
    for (int pi2 = 0; pi2 < 2; ++pi2) {
      int pr = 2 * wave + pi2;             // pair index 0..15
      int p2 = pr >> 2, n = pr & 3;
      int e_even = 2 * p2;
      int gA = 8 * p2 + n;                 // gcolA ; gcolB = gA+4
      float biasA = bcat[gA * 16 + lr];
      float biasB = bcat[(gA + 4) * 16 + lr];
      char* ebase = (char*)S.A2.e0B;
#pragma unroll
      for (int mt = 0; mt < 2; ++mt) {
#pragma unroll
        for (int rg = 0; rg < 4; ++rg) {
          int b = mt * 16 + lq * 4 + rg;
          float va = fmaxf(acc[mt][pi2 * 2 + 0][rg] + biasA, 0.f);
          float vb = fmaxf(acc[mt][pi2 * 2 + 1][rg] + biasB, 0.f);
          unsigned int pk = cvt_pk_bf16(va, vb);
          *(unsigned int*)(ebase + (b >> 1) * 2064 + (b & 1) * 256 + n * 512 +
                           lr * 16 + e_even * 2) = pk;
        }
      }
    }
#pragma unroll
    for (int i3 = 0; i3 < 3; ++i3) {
      int gcol = 32 + 3 * wave + i3;
      float bias = bcat[gcol * 16 + lr];
      int c2 = gcol - 32;                  // 0..23
      int u = c2 >> 1;
      int h = (c2 & 1) * 16 + lr;          // 0..31
      int kqw = h >> 3;
      int jw = h & 7;
#pragma unroll
      for (int mt = 0; mt < 2; ++mt) {
#pragma unroll
        for (int rg = 0; rg < 4; ++rg) {
          int row = mt * 16 + lq * 4 + rg;
          float v = acc[mt][4 + i3][rg] + bias;
          S.U.a.YgA[u * 1024 + row * 32 + ((kqw ^ (int)s2f(row)) << 3) + jw] =
              f2b(v > 0.f ? v : 0.f);
        }
      }
    }
  }
  __syncthreads();
  __builtin_amdgcn_sched_barrier(0);

  // ---- P3: gate logits via MFMA + cross-lane softmax ----
  // item id = u*2 + mt; wave handles ids 3w..3w+2 (24 items total)
  {
#pragma unroll
    for (int i = 0; i < 3; ++i) {
      int id = wave * 3 + i;
      int u = id >> 1;
      int mtq = id & 1;
      int row = lr + mtq * 16;           // batch row of this A row
      const char* yb = (const char*)S.U.a.YgA;
      short8 af = *(const short8*)(yb + u * 2048 + row * 64 +
                                   ((((unsigned int)lq) ^ s2f(row)) << 4));
      short8 bf = *(const short8*)(Bpack3 + (size_t)(u * 64 + lane) * 8);
      f32x4 dl = {0.f, 0.f, 0.f, 0.f};
      dl = __builtin_amdgcn_mfma_f32_16x16x32_bf16(af, bf, dl, 0, 0, 0);

      int col = lr;
      float bias = 0.f;
      if (col < 8) bias = (u < 8) ? bg0b[u * 8 + col] : bg1b[(u - 8) * 8 + col];
#pragma unroll
      for (int reg = 0; reg < 4; ++reg) {
        float lg = dl[reg] + bias;
        float m = lg;
        m = fmaxf(m, __shfl_xor(m, 1));
        m = fmaxf(m, __shfl_xor(m, 2));
        m = fmaxf(m, __shfl_xor(m, 4));
        float ex = __expf(lg - m);
        float s = ex;
        s += __shfl_xor(s, 1);
        s += __shfl_xor(s, 2);
        s += __shfl_xor(s, 4);
        float pv = ex / s;
        if (col < 8) {
          int b = mtq * 16 + lq * 4 + reg;
          if (u < 8) S.g0L[b * 64 + u * 8 + col] = f2b(pv);
          else       S.g1L[b * 32 + (u - 8) * 8 + col] = f2b(pv);
        }
      }
    }
  }
  __syncthreads();
  __builtin_amdgcn_sched_barrier(0);

  // ---- P4: x1 = g0 @ e0 via block-diagonal MFMA ----
  // pair p (rows 2p,2p+1): A(16x32): A[(bi*8+g)][bi'*8+e] = (bi==bi') g0[2p+bi][g][e]
  // B = e0B[p][n];  D[row=(bi*8+g)][col=hcol] = x1[2p+bi][g][n*16+hcol]
  {
    f32x4 xacc[2][4];
#pragma unroll
    for (int pi = 0; pi < 2; ++pi)
#pragma unroll
      for (int n = 0; n < 4; ++n) xacc[pi][n] = {0.f, 0.f, 0.f, 0.f};

    const short8 zero8 = {0, 0, 0, 0, 0, 0, 0, 0};
    const char* e0b = (const char*)S.A2.e0B;
#pragma unroll
    for (int pi = 0; pi < 2; ++pi) {
      int p = wave * 2 + pi;
      int kqh = lq & 1;
      int rtop = lr >> 3;
      int g = lane & 7;
      short8 ga = *(const short8*)&S.g0L[(2 * p + kqh) * 64 + g * 8];
      bool sel = (lane < 32) && (rtop == kqh);
      ga = sel ? ga : zero8;
#pragma unroll
      for (int n = 0; n < 4; ++n) {
        short8 bb = *(const short8*)(e0b + p * 2064 + n * 512 + (lane & 31) * 16);
        xacc[pi][n] = __builtin_amdgcn_mfma_f32_16x16x32_bf16(ga, bb, xacc[pi][n], 0, 0, 0);
      }
    }
    // write x1 -> x1A (bf16 A-frags for e1): element (E=g, b, h) at
    // byte = E*4096 + b*128 + ((chunk)<<4) + (h&7)*2,
    // chunk = (h>>3) ^ (b&7) ^ (((g>>2)&1)<<1)   (g-bit spreads write banks)
    char* x1b = (char*)S.U.x1A;
#pragma unroll
    for (int pi = 0; pi < 2; ++pi) {
      int p = wave * 2 + pi;
#pragma unroll
      for (int n = 0; n < 4; ++n) {
#pragma unroll
        for (int reg = 0; reg < 4; ++reg) {
          int row16 = lq * 4 + reg;
          int bi = row16 >> 3, g = row16 & 7;
          int b = 2 * p + bi;
          int h = n * 16 + lr;
          unsigned int chunk = ((unsigned int)(h >> 3)) ^ ((unsigned int)b & 7) ^
                               ((((unsigned int)g >> 2) & 1) << 1);
          *(unsigned short*)(x1b + g * 4096 + b * 128 + (chunk << 4) +
                             (h & 7) * 2) = f2b(xacc[pi][n][reg]);
        }
      }
    }
  }
  __syncthreads();
  __builtin_amdgcn_sched_barrier(0);

  // ---- P5: e1 = relu(x1 @ We1 + be1) via MFMA.  wave w = expert w ----
  // B fragments loaded per-ks (max 8 dwords live), from L2-resident Bpack2.
  {
    const int w = wave;
    f32x4 eacc[2][2];
#pragma unroll
    for (int mt = 0; mt < 2; ++mt)
#pragma unroll
      for (int ct = 0; ct < 2; ++ct) eacc[mt][ct] = {0.f, 0.f, 0.f, 0.f};

    const char* x1b = (const char*)S.U.x1A;
    const unsigned int gbit = (((unsigned int)w >> 2) & 1) << 1;
#pragma unroll
    for (int ks = 0; ks < 2; ++ks) {
      short8 b0 = *(const short8*)(Bpack2 + (size_t)(w * 4 + 0 * 2 + ks) * 512 + lane * 8);
      short8 b1 = *(const short8*)(Bpack2 + (size_t)(w * 4 + 1 * 2 + ks) * 512 + lane * 8);
#pragma unroll
      for (int mt = 0; mt < 2; ++mt) {
        int bp_ = lr + 16 * mt;
        unsigned int chunk = (((unsigned int)(ks * 4 + lq)) ^ ((unsigned int)bp_ & 7)) ^ gbit;
        short8 a = *(const short8*)(x1b + w * 4096 + bp_ * 128 + (chunk << 4));
        eacc[mt][0] = __builtin_amdgcn_mfma_f32_16x16x32_bf16(a, b0, eacc[mt][0], 0, 0, 0);
        eacc[mt][1] = __builtin_amdgcn_mfma_f32_16x16x32_bf16(a, b1, eacc[mt][1], 0, 0, 0);
      }
    }
    unsigned short* e1buf = S.A2.e1buf;
#pragma unroll
    for (int ct = 0; ct < 2; ++ct) {
      int k = ct * 16 + lr;
      float bias = be1[w * 32 + k];
#pragma unroll
      for (int mt = 0; mt < 2; ++mt) {
#pragma unroll
        for (int rg = 0; rg < 4; ++rg) {
          int row = mt * 16 + lq * 4 + rg;
          float v = eacc[mt][ct][rg] + bias;
          e1buf[row * 274 + w * 34 + k] = f2b(v > 0.f ? v : 0.f);
        }
      }
    }
  }
  __syncthreads();
  __builtin_amdgcn_sched_barrier(0);

  // ---- P6: out[t][k] = sum_e g1[t][e]*e1[e][k].  thread (r,j) owns k={2j,2j+1}.
  //      Gate probs read as scalar LDS broadcasts at use (no gvt[] array). ----
  {
    const int r = tid >> 4;
    const int j = tid & 15;
    const unsigned short* e1buf = S.A2.e1buf;
    float o0[4], o1[4];
#pragma unroll
    for (int t = 0; t < 4; ++t) { o0[t] = 0.f; o1[t] = 0.f; }
#pragma unroll
    for (int q = 0; q < 8; ++q) {
      unsigned int uu = *(const unsigned int*)&e1buf[r * 274 + q * 34 + j * 2];
      float ev0, ev1;
      unpack2(uu, ev0, ev1);
#pragma unroll
      for (int t = 0; t < 4; ++t) {
        float gt = b2f(S.g1L[r * 32 + t * 8 + q]);
        o0[t] += gt * ev0;
        o1[t] += gt * ev1;
      }
    }
    float* op = out + ((size_t)bid * 32 + r) * 128 + j * 2;
#pragma unroll
    for (int t = 0; t < 4; ++t) {
      *(float2*)(op + t * 32) = make_float2(o0[t], o1[t]);
    }
  }
}

extern "C" void kernel_launch(void* const* d_in, const int* in_sizes, int n_in,
                              void* d_out, int out_size, void* d_ws, size_t ws_size,
                              hipStream_t stream) {
  const float* x    = (const float*)d_in[0];
  const float* We0  = (const float*)d_in[1];
  const float* be0  = (const float*)d_in[2];
  const float* We1  = (const float*)d_in[3];
  const float* be1  = (const float*)d_in[4];
  const float* Wg0a = (const float*)d_in[5];
  const float* bg0a = (const float*)d_in[6];
  const float* Wg0b = (const float*)d_in[7];
  const float* bg0b = (const float*)d_in[8];
  const float* Wg1a = (const float*)d_in[9];
  const float* bg1a = (const float*)d_in[10];
  const float* Wg1b = (const float*)d_in[11];
  const float* bg1b = (const float*)d_in[12];

  unsigned short* Bpack  = (unsigned short*)d_ws;
  float*          bcat   = (float*)((char*)d_ws + 458752);
  unsigned short* Bpack2 = (unsigned short*)((char*)d_ws + 462336);
  unsigned short* Bpack3 = (unsigned short*)((char*)d_ws + 495104);

  pack_kernel<<<492, 512, 0, stream>>>(We0, Wg0a, Wg1a, be0, bg0a, bg1a, We1,
                                       Wg0b, Wg1b, Bpack, bcat, Bpack2, Bpack3);
  fused_kernel<<<2048, 512, 0, stream>>>(x, Bpack, bcat, Bpack2, Bpack3, be1,
                                         bg0b, bg1b, (float*)d_out);
}